// Round 8
// baseline (532.027 us; speedup 1.0000x reference)
//
#include <hip/hip_runtime.h>
#include <hip/hip_bf16.h>

#define NCN 10000   // computation nodes
#define ECN 120000  // computation edges
#define NHH 256     // hidden
#define CEE 16      // cedge feat dim
#define GCN 100     // cgroups
#define GSZ 100     // nodes per cgroup
#define NTT 16      // topo nodes
#define ETT 64      // topo edges
#define TGG 8       // tgroups
#define OPEE 4
#define CFF 64
#define TFF 32
#define TEE 16
#define NPB 8       // dst nodes per block in GEMM kernels
#define HFW 272     // hf row width (256 + 16 eagg)
#define HFW0 88     // layer-0 hf row width (64 cf + 4 ope + s_on + pad + 16 eaggR)

// ---------- static device scratch (no d_ws dependency) ----------
__device__ int   g_indeg[NCN];
__device__ int   g_outdeg[NCN];
__device__ int   g_cursor[NCN];
__device__ int   g_off[NCN+1];
__device__ int   g_eid[ECN];
__device__ int   g_srcarr[ECN];
__device__ float g_onorm[NCN];
__device__ float g_inorm[NCN];
__device__ float g_eagg [NCN*CEE];
__device__ float g_eaggR[NCN*CEE];
__device__ float g_tx0[NTT*NHH];
__device__ float g_tx1[NTT*NHH];
__device__ float g_v0p[TGG*NHH];
__device__ float g_v0[NHH];
__device__ float g_x0[(size_t)NCN*NHH];   // xn (normalized state) / final raw
__device__ float g_x1[(size_t)NCN*NHH];
__device__ float g_hf[(size_t)NCN*HFW];
__device__ float g_cembp[4*GCN*NHH];

__device__ __forceinline__ int clampi(int v,int lo,int hi){ return v<lo?lo:(v>hi?hi:v); }

__global__ __launch_bounds__(256) void k_badsize(float* out, int n, float code){
    int i = blockIdx.x*256 + threadIdx.x;
    if (i < n) out[i] = code;
}

// ---------------- graph prep ----------------
__global__ __launch_bounds__(256) void k_zero3(){
    int i = blockIdx.x*256 + threadIdx.x;
    if (i < NCN){ g_indeg[i]=0; g_outdeg[i]=0; g_cursor[i]=0; }
}

__global__ __launch_bounds__(256) void k_degrees(const int* __restrict__ src, const int* __restrict__ dst){
    int e = blockIdx.x*256 + threadIdx.x;
    if (e < ECN){
        atomicAdd(&g_outdeg[clampi(src[e],0,NCN-1)],1);
        atomicAdd(&g_indeg [clampi(dst[e],0,NCN-1)],1);
    }
}

__global__ __launch_bounds__(256) void k_norms(){
    int i = blockIdx.x*256 + threadIdx.x;
    if (i < NCN){
        g_onorm[i] = rsqrtf((float)max(g_outdeg[i],1));
        g_inorm[i] = rsqrtf((float)max(g_indeg[i],1));
    }
}

__global__ __launch_bounds__(1024) void k_scan(){
    __shared__ int cs[1024];
    const int CH = (NCN + 1023)/1024;
    int t = threadIdx.x;
    int base = t*CH;
    int s = 0;
    for (int j=0;j<CH;j++){ int idx=base+j; if (idx<NCN) s += g_indeg[idx]; }
    cs[t] = s; __syncthreads();
    for (int ofs=1; ofs<1024; ofs<<=1){
        int v = (t>=ofs) ? cs[t-ofs] : 0;
        __syncthreads();
        cs[t] += v;
        __syncthreads();
    }
    int run = (t==0) ? 0 : cs[t-1];
    for (int j=0;j<CH;j++){
        int idx = base+j;
        if (idx <= NCN) g_off[idx] = run;
        if (idx < NCN) run += g_indeg[idx];
    }
}

__global__ __launch_bounds__(256) void k_scatter(const int* __restrict__ dst){
    int e = blockIdx.x*256 + threadIdx.x;
    if (e < ECN){
        int d = clampi(dst[e],0,NCN-1);
        int pos = g_off[d] + atomicAdd(&g_cursor[d],1);
        g_eid[clampi(pos,0,ECN-1)] = e;
    }
}

__global__ __launch_bounds__(256) void k_sortfill(const int* __restrict__ c_src){
    int d = blockIdx.x*256 + threadIdx.x;
    if (d < NCN){
        int b = clampi(g_off[d],0,ECN), e = clampi(g_off[d+1],b,ECN);
        for (int i=b+1;i<e;i++){
            int key = g_eid[i]; int j = i-1;
            while (j>=b && g_eid[j]>key){ g_eid[j+1]=g_eid[j]; j--; }
            g_eid[j+1] = key;
        }
        for (int i=b;i<e;i++) g_srcarr[i] = clampi(c_src[clampi(g_eid[i],0,ECN-1)],0,NCN-1);
    }
}

__global__ __launch_bounds__(256) void k_eagg(const float* __restrict__ ef){
    int d = blockIdx.x*16 + threadIdx.x/16;
    int f = threadIdx.x%16;
    if (d < NCN){
        float s=0.f, sr=0.f;
        int b=clampi(g_off[d],0,ECN), e=clampi(g_off[d+1],b,ECN);
        for (int i=b;i<e;i++){
            float v = ef[(size_t)clampi(g_eid[i],0,ECN-1)*CEE + f];
            s += v; sr += fmaxf(v,0.f);
        }
        g_eagg [(size_t)d*CEE+f] = s;
        g_eaggR[(size_t)d*CEE+f] = sr;
    }
}

// ---- topo helpers ----
__device__ __forceinline__ void topo_edges_norms(
    const int* __restrict__ t_src, const int* __restrict__ t_dst,
    int* ssrc, int* sdst, int* sdeg, float* onrm, float* inrm, int t)
{
    if (t < 2*NTT) sdeg[t]=0;
    __syncthreads();
    if (t < ETT){
        int s=clampi(t_src[t],0,NTT-1), d=clampi(t_dst[t],0,NTT-1);
        ssrc[t]=s; sdst[t]=d;
        atomicAdd(&sdeg[s],1); atomicAdd(&sdeg[NTT+d],1);
    }
    __syncthreads();
    if (t < NTT){
        onrm[t]=rsqrtf((float)max(sdeg[t],1));
        inrm[t]=rsqrtf((float)max(sdeg[NTT+t],1));
    }
    __syncthreads();
}

__global__ __launch_bounds__(256) void kt_l0(
    const float* __restrict__ tfeats, const float* __restrict__ tef,
    const float* __restrict__ tW0, const float* __restrict__ tb0,
    const int* __restrict__ t_src, const int* __restrict__ t_dst)
{
    __shared__ float h[48];
    __shared__ int ssrc[ETT], sdst[ETT], sdeg[2*NTT];
    __shared__ float onrm[NTT], inrm[NTT];
    const int d = blockIdx.x, t = threadIdx.x;
    topo_edges_norms(t_src, t_dst, ssrc, sdst, sdeg, onrm, inrm, t);
    if (t < 48){
        float acc=0.f;
        for (int e=0;e<ETT;e++){
            if (sdst[e]==d){
                int s=ssrc[e];
                float v = (t<TFF) ? tfeats[s*TFF+t]*onrm[s] : tef[e*TEE+(t-TFF)];
                acc += fmaxf(v,0.f);
            }
        }
        h[t]=acc;
    }
    __syncthreads();
    float acc=0.f;
    for (int k=0;k<48;k++) acc += h[k]*tW0[k*NHH+t];
    g_tx0[d*NHH+t] = fmaxf(acc*inrm[d]+tb0[t], 0.f);
}

template<int DIR>
__global__ __launch_bounds__(256) void kt_lr(
    const float* __restrict__ tef,
    const float* __restrict__ W, const float* __restrict__ bias,
    const int* __restrict__ t_src, const int* __restrict__ t_dst, int relu_res)
{
    const float* xin  = DIR ? g_tx1 : g_tx0;
    float*       xout = DIR ? g_tx0 : g_tx1;
    __shared__ float h[NHH+TEE];
    __shared__ int ssrc[ETT], sdst[ETT], sdeg[2*NTT];
    __shared__ float onrm[NTT], inrm[NTT];
    const int d = blockIdx.x, t = threadIdx.x;
    topo_edges_norms(t_src, t_dst, ssrc, sdst, sdeg, onrm, inrm, t);
    {
        float a0=0.f, a1=0.f;
        for (int e=0;e<ETT;e++){
            if (sdst[e]==d){
                a0 += xin[ssrc[e]*NHH+t]*onrm[ssrc[e]];
                if (t<TEE) a1 += tef[e*TEE+t];
            }
        }
        h[t]=a0;
        if (t<TEE) h[NHH+t]=a1;
    }
    __syncthreads();
    float acc=0.f;
    for (int k=0;k<NHH+TEE;k++) acc += h[k]*W[(size_t)k*NHH+t];
    float val = acc*inrm[d] + bias[t];
    xout[d*NHH+t] = relu_res ? (xin[d*NHH+t]*onrm[d] + fmaxf(val,0.f)) : val;
}

__global__ __launch_bounds__(256) void k_v0(const float* __restrict__ cW0, const int* __restrict__ tgroups){
    __shared__ float srt[NHH];
    int b=blockIdx.x, c=threadIdx.x;
    int i0=clampi(tgroups[b*2+0],0,NTT-1), i1=clampi(tgroups[b*2+1],0,NTT-1);
    srt[c]=fmaxf(g_tx1[i0*NHH+c]+g_tx1[i1*NHH+c],0.f);
    __syncthreads();
    const float* Wm = cW0 + (size_t)(CFF+OPEE + b*NHH)*NHH;
    float acc=0.f;
    for (int j=0;j<NHH;j++) acc += srt[j]*Wm[(size_t)j*NHH+c];
    g_v0p[b*NHH+c]=acc;
}
__global__ __launch_bounds__(256) void k_v0r(){
    int c=threadIdx.x;
    float s=0.f;
    for (int b=0;b<TGG;b++) s+=g_v0p[b*NHH+c];
    g_v0[c]=s;
}

// ---------------- layer-0 gather: one wave per node ----------------
// hf0 row (width 88): [0:64] sum relu(cfeats)*on | [64:68] sum relu(opemb)*on | [68] s_on | [69:72]=0 | [72:88] eaggR
__global__ __launch_bounds__(256) void k_gather0(
    const int* __restrict__ ctypes,
    const float* __restrict__ cfeats, const float* __restrict__ opemb)
{
    const int wv = threadIdx.x >> 6, lane = threadIdx.x & 63;
    const int d = blockIdx.x*4 + wv;
    int b = g_off[d], e = g_off[d+1];
    float a_cf=0.f, a_op=0.f, aon=0.f;
    for (int i=b;i<e;i++){
        int s = g_srcarr[i];
        float on = g_onorm[s];
        a_cf += fmaxf(cfeats[(size_t)s*CFF+lane],0.f)*on;
        if (lane < OPEE){
            int ct = clampi(ctypes[s],0,255);
            a_op += fmaxf(opemb[ct*OPEE+lane],0.f)*on;
        }
        aon += on;
    }
    float* row = g_hf + (size_t)d*HFW0;
    row[lane] = a_cf;
    if (lane < OPEE)  row[CFF+lane] = a_op;
    if (lane == 4)    row[68] = aon;
    if (lane >= 5 && lane < 8) row[64+lane] = 0.f;
    if (lane >= 8 && lane < 24) row[72+(lane-8)] = g_eaggR[(size_t)d*CEE+(lane-8)];
}

// ---------------- layer-0 GEMM: writes xn0 = relu(.)*onorm ----------------
__global__ __launch_bounds__(256) void k_gemm0(
    const float* __restrict__ cW0, const float* __restrict__ cb0)
{
    __shared__ float sh[NPB][HFW0];
    const int d0 = blockIdx.x*NPB;
    const int t = threadIdx.x, lane = t & 63, q = t >> 6;
    for (int i=t; i<NPB*(HFW0/4); i+=256){
        int n = i/(HFW0/4), k4 = i%(HFW0/4);
        ((float4*)&sh[n][0])[k4] = ((const float4*)(g_hf + (size_t)(d0+n)*HFW0))[k4];
    }
    __syncthreads();
    const int col = q*64 + lane;
    float acc[NPB];
    #pragma unroll
    for (int n=0;n<NPB;n++) acc[n]=0.f;
    for (int k4=0;k4<16;k4++){
        float w0=cW0[(size_t)(4*k4+0)*NHH+col];
        float w1=cW0[(size_t)(4*k4+1)*NHH+col];
        float w2=cW0[(size_t)(4*k4+2)*NHH+col];
        float w3=cW0[(size_t)(4*k4+3)*NHH+col];
        #pragma unroll
        for (int n=0;n<NPB;n++){
            float4 h4 = *((const float4*)&sh[n][4*k4]);
            acc[n] += h4.x*w0 + h4.y*w1 + h4.z*w2 + h4.w*w3;
        }
    }
    #pragma unroll
    for (int k=0;k<OPEE;k++){
        float w=cW0[(size_t)(CFF+k)*NHH+col];
        #pragma unroll
        for (int n=0;n<NPB;n++) acc[n]+=sh[n][CFF+k]*w;
    }
    {
        float w=g_v0[col];
        #pragma unroll
        for (int n=0;n<NPB;n++) acc[n]+=sh[n][68]*w;
    }
    const float* We = cW0 + (size_t)(CFF+OPEE+TGG*NHH)*NHH;
    for (int f4=0;f4<4;f4++){
        float w0=We[(size_t)(4*f4+0)*NHH+col];
        float w1=We[(size_t)(4*f4+1)*NHH+col];
        float w2=We[(size_t)(4*f4+2)*NHH+col];
        float w3=We[(size_t)(4*f4+3)*NHH+col];
        #pragma unroll
        for (int n=0;n<NPB;n++){
            float4 h4 = *((const float4*)&sh[n][72+4*f4]);
            acc[n] += h4.x*w0 + h4.y*w1 + h4.z*w2 + h4.w*w3;
        }
    }
    float bb=cb0[col];
    #pragma unroll
    for (int n=0;n<NPB;n++){
        int d=d0+n;
        g_x0[(size_t)d*NHH+col]=fmaxf(acc[n]*g_inorm[d]+bb,0.f)*g_onorm[d];
    }
}

// ---------------- recurrent gather: one wave per node, xn is pre-normalized ----------------
template<int DIR>   // DIR=0: read g_x0, DIR=1: read g_x1
__global__ __launch_bounds__(256) void k_gather(){
    const float* xn = DIR ? g_x1 : g_x0;
    const int wv = threadIdx.x >> 6, lane = threadIdx.x & 63;
    const int d = blockIdx.x*4 + wv;
    int b = g_off[d], e = g_off[d+1];
    float4 a = make_float4(0.f,0.f,0.f,0.f);
    int i = b;
    for (; i+1 < e; i += 2){
        int s0 = g_srcarr[i], s1 = g_srcarr[i+1];
        float4 v0 = *((const float4*)(xn + (size_t)s0*NHH) + lane);
        float4 v1 = *((const float4*)(xn + (size_t)s1*NHH) + lane);
        a.x += v0.x; a.y += v0.y; a.z += v0.z; a.w += v0.w;
        a.x += v1.x; a.y += v1.y; a.z += v1.z; a.w += v1.w;
    }
    if (i < e){
        int s0 = g_srcarr[i];
        float4 v0 = *((const float4*)(xn + (size_t)s0*NHH) + lane);
        a.x += v0.x; a.y += v0.y; a.z += v0.z; a.w += v0.w;
    }
    float* row = g_hf + (size_t)d*HFW;
    *((float4*)row + lane) = a;
    if (lane < CEE) row[NHH+lane] = g_eagg[(size_t)d*CEE+lane];
}

// ---------------- recurrent GEMM: epilogue writes xn (or raw for last layer) ----------------
template<int DIR>   // DIR=0: residual/in g_x0 -> out g_x1; DIR=1: reverse
__global__ __launch_bounds__(256) void k_gemmr(
    const float* __restrict__ W, const float* __restrict__ bias, int relu_res)
{
    const float* xnin = DIR ? g_x1 : g_x0;
    float*       xout = DIR ? g_x0 : g_x1;
    __shared__ float sh[NPB][HFW];
    const int d0 = blockIdx.x*NPB;
    const int t = threadIdx.x, lane = t & 63, q = t >> 6;
    for (int i=t; i<NPB*(HFW/4); i+=256){
        int n = i/(HFW/4), k4 = i%(HFW/4);
        ((float4*)&sh[n][0])[k4] = ((const float4*)(g_hf + (size_t)(d0+n)*HFW))[k4];
    }
    __syncthreads();
    const int col = q*64 + lane;
    float acc[NPB];
    #pragma unroll
    for (int n=0;n<NPB;n++) acc[n]=0.f;
    for (int k4=0;k4<HFW/4;k4++){
        float w0=W[(size_t)(4*k4+0)*NHH+col];
        float w1=W[(size_t)(4*k4+1)*NHH+col];
        float w2=W[(size_t)(4*k4+2)*NHH+col];
        float w3=W[(size_t)(4*k4+3)*NHH+col];
        #pragma unroll
        for (int n=0;n<NPB;n++){
            float4 h4 = *((const float4*)&sh[n][4*k4]);
            acc[n] += h4.x*w0 + h4.y*w1 + h4.z*w2 + h4.w*w3;
        }
    }
    float bb = bias[col];
    #pragma unroll
    for (int n=0;n<NPB;n++){
        int d = d0+n;
        float val = acc[n]*g_inorm[d]+bb;
        if (relu_res){
            float y = xnin[(size_t)d*NHH+col] + fmaxf(val,0.f);  // residual on normalized feat
            xout[(size_t)d*NHH+col] = y*g_onorm[d];              // pre-normalize for next layer
        } else {
            xout[(size_t)d*NHH+col] = val;                        // final layer: raw
        }
    }
}

// ---------------- pooling (4 deterministic partials) + heads ----------------
__global__ __launch_bounds__(256) void k_cemb(const int* __restrict__ cgroups){
    int g=blockIdx.x>>2, p=blockIdx.x&3, c=threadIdx.x;
    float s=0.f;
    for (int i=p*25;i<p*25+25;i++){
        int idx=clampi(cgroups[g*GSZ+i],0,NCN-1);
        s += g_x1[(size_t)idx*NHH+c];
    }
    g_cembp[(size_t)(p*GCN+g)*NHH+c]=s;
}

__global__ __launch_bounds__(256) void k_heads(
    const float* __restrict__ sW, const float* __restrict__ sb,
    const float* __restrict__ nW, const float* __restrict__ nb, float* __restrict__ out)
{
    __shared__ float red[256];
    __shared__ float z[9];
    int g=blockIdx.x, t=threadIdx.x;
    float e = g_cembp[(size_t)(0*GCN+g)*NHH+t] + g_cembp[(size_t)(1*GCN+g)*NHH+t]
            + g_cembp[(size_t)(2*GCN+g)*NHH+t] + g_cembp[(size_t)(3*GCN+g)*NHH+t];
    for (int j=0;j<9;j++){
        float w = (j==0) ? nW[t] : sW[t*TGG+(j-1)];
        red[t]=e*w; __syncthreads();
        for (int s=128;s>0;s>>=1){ if (t<s) red[t]+=red[t+s]; __syncthreads(); }
        if (t==0) z[j]=red[0];
        __syncthreads();
    }
    if (t==0){
        float z0 = z[0] + nb[0];
        float lsig = fminf(z0,0.f) - log1pf(expf(-fabsf(z0)));
        out[g*9+0]=lsig;
        float zz[8]; float m=-1e30f;
        for (int j=0;j<8;j++){ zz[j]=z[j+1]+sb[j]; m=fmaxf(m,zz[j]); }
        float s=0.f;
        for (int j=0;j<8;j++) s+=expf(zz[j]-m);
        float lse=m+logf(s);
        for (int j=0;j<8;j++) out[g*9+1+j]=zz[j]-lse;
    }
}

extern "C" void kernel_launch(void* const* d_in, const int* in_sizes, int n_in,
                              void* d_out, int out_size, void* d_ws, size_t ws_size,
                              hipStream_t stream) {
    const int expect[24] = {
        NCN*CFF, ECN*CEE, NTT*TFF, ETT*TEE, 256*OPEE,
        (TFF+TEE)*NHH, NHH, 3*(NHH+TEE)*NHH, 3*NHH,
        (CFF+OPEE+TGG*NHH+CEE)*NHH, NHH, 5*(NHH+CEE)*NHH, 5*NHH,
        NHH*TGG, TGG, NHH, 1,
        NCN, ECN, ECN, ETT, ETT, GCN*GSZ, TGG*2
    };
    if (n_in < 24){
        k_badsize<<<(out_size+255)/256,256,0,stream>>>((float*)d_out, out_size, 2.0e6f);
        return;
    }
    for (int i=0;i<24;i++){
        if (in_sizes[i] != expect[i]){
            k_badsize<<<(out_size+255)/256,256,0,stream>>>((float*)d_out, out_size, 1.0e6f+(float)i);
            return;
        }
    }

    const float* cfeats = (const float*)d_in[0];
    const float* cef    = (const float*)d_in[1];
    const float* tfeats = (const float*)d_in[2];
    const float* tef    = (const float*)d_in[3];
    const float* opemb  = (const float*)d_in[4];
    const float* tW0    = (const float*)d_in[5];
    const float* tb0    = (const float*)d_in[6];
    const float* tWr    = (const float*)d_in[7];
    const float* tbr    = (const float*)d_in[8];
    const float* cW0    = (const float*)d_in[9];
    const float* cb0    = (const float*)d_in[10];
    const float* cWr    = (const float*)d_in[11];
    const float* cbr    = (const float*)d_in[12];
    const float* sW     = (const float*)d_in[13];
    const float* sb     = (const float*)d_in[14];
    const float* nW     = (const float*)d_in[15];
    const float* nb     = (const float*)d_in[16];
    const int* ctypes   = (const int*)d_in[17];
    const int* c_src    = (const int*)d_in[18];
    const int* c_dst    = (const int*)d_in[19];
    const int* t_src    = (const int*)d_in[20];
    const int* t_dst    = (const int*)d_in[21];
    const int* cgroups  = (const int*)d_in[22];
    const int* tgroups  = (const int*)d_in[23];

    const int EB = (ECN+255)/256, NB = (NCN+255)/256;

    k_zero3   <<<NB, 256, 0, stream>>>();
    k_degrees <<<EB, 256, 0, stream>>>(c_src, c_dst);
    k_norms   <<<NB, 256, 0, stream>>>();
    k_scan    <<<1, 1024, 0, stream>>>();
    k_scatter <<<EB, 256, 0, stream>>>(c_dst);
    k_sortfill<<<NB, 256, 0, stream>>>(c_src);
    k_eagg    <<<(NCN+15)/16, 256, 0, stream>>>(cef);

    // topo GNN
    kt_l0    <<<NTT, 256, 0, stream>>>(tfeats, tef, tW0, tb0, t_src, t_dst);
    kt_lr<0> <<<NTT, 256, 0, stream>>>(tef, tWr + (size_t)0*(NHH+TEE)*NHH, tbr + 0*NHH, t_src, t_dst, 1);
    kt_lr<1> <<<NTT, 256, 0, stream>>>(tef, tWr + (size_t)1*(NHH+TEE)*NHH, tbr + 1*NHH, t_src, t_dst, 1);
    kt_lr<0> <<<NTT, 256, 0, stream>>>(tef, tWr + (size_t)2*(NHH+TEE)*NHH, tbr + 2*NHH, t_src, t_dst, 0);
    k_v0     <<<TGG, 256, 0, stream>>>(cW0, tgroups);
    k_v0r    <<<1, 256, 0, stream>>>();

    // cGNN layer 0 (gather + GEMM), xn0 -> g_x0
    k_gather0<<<NCN/4, 256, 0, stream>>>(ctypes, cfeats, opemb);
    k_gemm0  <<<NCN/NPB, 256, 0, stream>>>(cW0, cb0);

    // 5 recurrent layers: xn ping-pong x0 -> x1 -> x0 -> x1 -> x0 -> x1 (final raw in g_x1)
    k_gather<0><<<NCN/4, 256, 0, stream>>>();
    k_gemmr <0><<<NCN/NPB, 256, 0, stream>>>(cWr + (size_t)0*(NHH+CEE)*NHH, cbr + 0*NHH, 1);
    k_gather<1><<<NCN/4, 256, 0, stream>>>();
    k_gemmr <1><<<NCN/NPB, 256, 0, stream>>>(cWr + (size_t)1*(NHH+CEE)*NHH, cbr + 1*NHH, 1);
    k_gather<0><<<NCN/4, 256, 0, stream>>>();
    k_gemmr <0><<<NCN/NPB, 256, 0, stream>>>(cWr + (size_t)2*(NHH+CEE)*NHH, cbr + 2*NHH, 1);
    k_gather<1><<<NCN/4, 256, 0, stream>>>();
    k_gemmr <1><<<NCN/NPB, 256, 0, stream>>>(cWr + (size_t)3*(NHH+CEE)*NHH, cbr + 3*NHH, 1);
    k_gather<0><<<NCN/4, 256, 0, stream>>>();
    k_gemmr <0><<<NCN/NPB, 256, 0, stream>>>(cWr + (size_t)4*(NHH+CEE)*NHH, cbr + 4*NHH, 0);

    k_cemb <<<4*GCN, 256, 0, stream>>>(cgroups);
    k_heads<<<GCN, 256, 0, stream>>>(sW, sb, nW, nb, (float*)d_out);
}

// Round 9
// 435.505 us; speedup vs baseline: 1.2216x; 1.2216x over previous
//
#include <hip/hip_runtime.h>
#include <hip/hip_bf16.h>

#define NCN 10000   // computation nodes
#define ECN 120000  // computation edges
#define NHH 256     // hidden
#define CEE 16      // cedge feat dim
#define GCN 100     // cgroups
#define GSZ 100     // nodes per cgroup
#define NTT 16      // topo nodes
#define ETT 64      // topo edges
#define TGG 8       // tgroups
#define OPEE 4
#define CFF 64
#define TFF 32
#define TEE 16
#define NPB 8       // dst nodes per block in GEMM kernels
#define HFW 272     // hf row width (256 + 16 eagg)
#define HFW0 88     // layer-0 hf row width (64 cf + 4 ope + s_on + pad + 16 eaggR)

// ---------- static device scratch (no d_ws dependency) ----------
__device__ int   g_indeg[NCN];
__device__ int   g_outdeg[NCN];
__device__ int   g_cursor[NCN];
__device__ int   g_off[NCN+1];
__device__ int   g_eid[ECN];
__device__ int   g_srcarr[ECN];
__device__ float g_onorm[NCN];
__device__ float g_inorm[NCN];
__device__ float g_eagg [NCN*CEE];
__device__ float g_eaggR[NCN*CEE];
__device__ float g_tx0[NTT*NHH];
__device__ float g_tx1[NTT*NHH];
__device__ float g_v0p[TGG*NHH];
__device__ float g_v0[NHH];
__device__ float g_x0[(size_t)NCN*NHH];   // xn (normalized state) / final raw
__device__ float g_x1[(size_t)NCN*NHH];
__device__ float g_hf[(size_t)NCN*HFW];
__device__ float g_cembp[4*GCN*NHH];

__device__ __forceinline__ int clampi(int v,int lo,int hi){ return v<lo?lo:(v>hi?hi:v); }

__global__ __launch_bounds__(256) void k_badsize(float* out, int n, float code){
    int i = blockIdx.x*256 + threadIdx.x;
    if (i < n) out[i] = code;
}

// ---------------- graph prep ----------------
__global__ __launch_bounds__(256) void k_zero3(){
    int i = blockIdx.x*256 + threadIdx.x;
    if (i < NCN){ g_indeg[i]=0; g_outdeg[i]=0; g_cursor[i]=0; }
}

__global__ __launch_bounds__(256) void k_degrees(const int* __restrict__ src, const int* __restrict__ dst){
    int e = blockIdx.x*256 + threadIdx.x;
    if (e < ECN){
        atomicAdd(&g_outdeg[clampi(src[e],0,NCN-1)],1);
        atomicAdd(&g_indeg [clampi(dst[e],0,NCN-1)],1);
    }
}

__global__ __launch_bounds__(256) void k_norms(){
    int i = blockIdx.x*256 + threadIdx.x;
    if (i < NCN){
        g_onorm[i] = rsqrtf((float)max(g_outdeg[i],1));
        g_inorm[i] = rsqrtf((float)max(g_indeg[i],1));
    }
}

__global__ __launch_bounds__(1024) void k_scan(){
    __shared__ int cs[1024];
    const int CH = (NCN + 1023)/1024;
    int t = threadIdx.x;
    int base = t*CH;
    int s = 0;
    for (int j=0;j<CH;j++){ int idx=base+j; if (idx<NCN) s += g_indeg[idx]; }
    cs[t] = s; __syncthreads();
    for (int ofs=1; ofs<1024; ofs<<=1){
        int v = (t>=ofs) ? cs[t-ofs] : 0;
        __syncthreads();
        cs[t] += v;
        __syncthreads();
    }
    int run = (t==0) ? 0 : cs[t-1];
    for (int j=0;j<CH;j++){
        int idx = base+j;
        if (idx <= NCN) g_off[idx] = run;
        if (idx < NCN) run += g_indeg[idx];
    }
}

__global__ __launch_bounds__(256) void k_scatter(const int* __restrict__ dst){
    int e = blockIdx.x*256 + threadIdx.x;
    if (e < ECN){
        int d = clampi(dst[e],0,NCN-1);
        int pos = g_off[d] + atomicAdd(&g_cursor[d],1);
        g_eid[clampi(pos,0,ECN-1)] = e;
    }
}

// wave-per-node bitonic sort of eid (deterministic order) + srcarr fill
__global__ __launch_bounds__(256) void k_sortfill(const int* __restrict__ c_src){
    const int wv = threadIdx.x >> 6, lane = threadIdx.x & 63;
    const int d = blockIdx.x*4 + wv;
    int b = clampi(g_off[d],0,ECN), e = clampi(g_off[d+1],b,ECN);
    int deg = e - b;
    if (deg <= 64){
        int v = (lane < deg) ? g_eid[b+lane] : 0x7fffffff;
        #pragma unroll
        for (int k=2;k<=64;k<<=1){
            #pragma unroll
            for (int j=k>>1;j>0;j>>=1){
                int p = __shfl_xor(v, j, 64);
                bool takeMin = ((lane & j)==0) == ((lane & k)==0);
                v = takeMin ? min(v,p) : max(v,p);
            }
        }
        if (lane < deg){
            g_eid[b+lane] = v;
            g_srcarr[b+lane] = clampi(c_src[clampi(v,0,ECN-1)],0,NCN-1);
        }
    } else if (lane == 0){
        for (int i=b+1;i<e;i++){
            int key = g_eid[i]; int j = i-1;
            while (j>=b && g_eid[j]>key){ g_eid[j+1]=g_eid[j]; j--; }
            g_eid[j+1] = key;
        }
        for (int i=b;i<e;i++) g_srcarr[i] = clampi(c_src[clampi(g_eid[i],0,ECN-1)],0,NCN-1);
    }
}

__global__ __launch_bounds__(256) void k_eagg(const float* __restrict__ ef){
    int d = blockIdx.x*16 + threadIdx.x/16;
    int f = threadIdx.x%16;
    if (d < NCN){
        float s=0.f, sr=0.f;
        int b=clampi(g_off[d],0,ECN), e=clampi(g_off[d+1],b,ECN);
        for (int i=b;i<e;i++){
            float v = ef[(size_t)clampi(g_eid[i],0,ECN-1)*CEE + f];
            s += v; sr += fmaxf(v,0.f);
        }
        g_eagg [(size_t)d*CEE+f] = s;
        g_eaggR[(size_t)d*CEE+f] = sr;
    }
}

// ---- topo helpers ----
__device__ __forceinline__ void topo_edges_norms(
    const int* __restrict__ t_src, const int* __restrict__ t_dst,
    int* ssrc, int* sdst, int* sdeg, float* onrm, float* inrm, int t)
{
    if (t < 2*NTT) sdeg[t]=0;
    __syncthreads();
    if (t < ETT){
        int s=clampi(t_src[t],0,NTT-1), d=clampi(t_dst[t],0,NTT-1);
        ssrc[t]=s; sdst[t]=d;
        atomicAdd(&sdeg[s],1); atomicAdd(&sdeg[NTT+d],1);
    }
    __syncthreads();
    if (t < NTT){
        onrm[t]=rsqrtf((float)max(sdeg[t],1));
        inrm[t]=rsqrtf((float)max(sdeg[NTT+t],1));
    }
    __syncthreads();
}

__global__ __launch_bounds__(256) void kt_l0(
    const float* __restrict__ tfeats, const float* __restrict__ tef,
    const float* __restrict__ tW0, const float* __restrict__ tb0,
    const int* __restrict__ t_src, const int* __restrict__ t_dst)
{
    __shared__ float h[48];
    __shared__ int ssrc[ETT], sdst[ETT], sdeg[2*NTT];
    __shared__ float onrm[NTT], inrm[NTT];
    const int d = blockIdx.x, t = threadIdx.x;
    topo_edges_norms(t_src, t_dst, ssrc, sdst, sdeg, onrm, inrm, t);
    if (t < 48){
        float acc=0.f;
        for (int e=0;e<ETT;e++){
            if (sdst[e]==d){
                int s=ssrc[e];
                float v = (t<TFF) ? tfeats[s*TFF+t]*onrm[s] : tef[e*TEE+(t-TFF)];
                acc += fmaxf(v,0.f);
            }
        }
        h[t]=acc;
    }
    __syncthreads();
    float acc=0.f;
    for (int k=0;k<48;k++) acc += h[k]*tW0[k*NHH+t];
    g_tx0[d*NHH+t] = fmaxf(acc*inrm[d]+tb0[t], 0.f);
}

template<int DIR>
__global__ __launch_bounds__(256) void kt_lr(
    const float* __restrict__ tef,
    const float* __restrict__ W, const float* __restrict__ bias,
    const int* __restrict__ t_src, const int* __restrict__ t_dst, int relu_res)
{
    const float* xin  = DIR ? g_tx1 : g_tx0;
    float*       xout = DIR ? g_tx0 : g_tx1;
    __shared__ float h[NHH+TEE];
    __shared__ int ssrc[ETT], sdst[ETT], sdeg[2*NTT];
    __shared__ float onrm[NTT], inrm[NTT];
    const int d = blockIdx.x, t = threadIdx.x;
    topo_edges_norms(t_src, t_dst, ssrc, sdst, sdeg, onrm, inrm, t);
    {
        float a0=0.f, a1=0.f;
        for (int e=0;e<ETT;e++){
            if (sdst[e]==d){
                a0 += xin[ssrc[e]*NHH+t]*onrm[ssrc[e]];
                if (t<TEE) a1 += tef[e*TEE+t];
            }
        }
        h[t]=a0;
        if (t<TEE) h[NHH+t]=a1;
    }
    __syncthreads();
    float acc=0.f;
    for (int k=0;k<NHH+TEE;k++) acc += h[k]*W[(size_t)k*NHH+t];
    float val = acc*inrm[d] + bias[t];
    xout[d*NHH+t] = relu_res ? (xin[d*NHH+t]*onrm[d] + fmaxf(val,0.f)) : val;
}

__global__ __launch_bounds__(256) void k_v0(const float* __restrict__ cW0, const int* __restrict__ tgroups){
    __shared__ float srt[NHH];
    int b=blockIdx.x, c=threadIdx.x;
    int i0=clampi(tgroups[b*2+0],0,NTT-1), i1=clampi(tgroups[b*2+1],0,NTT-1);
    srt[c]=fmaxf(g_tx1[i0*NHH+c]+g_tx1[i1*NHH+c],0.f);
    __syncthreads();
    const float* Wm = cW0 + (size_t)(CFF+OPEE + b*NHH)*NHH;
    float acc=0.f;
    for (int j=0;j<NHH;j++) acc += srt[j]*Wm[(size_t)j*NHH+c];
    g_v0p[b*NHH+c]=acc;
}
__global__ __launch_bounds__(256) void k_v0r(){
    int c=threadIdx.x;
    float s=0.f;
    for (int b=0;b<TGG;b++) s+=g_v0p[b*NHH+c];
    g_v0[c]=s;
}

// ---------------- layer-0 gather: one wave per node ----------------
// hf0 row (width 88): [0:64] sum relu(cfeats)*on | [64:68] sum relu(opemb)*on | [68] s_on | [69:72]=0 | [72:88] eaggR
__global__ __launch_bounds__(256) void k_gather0(
    const int* __restrict__ ctypes,
    const float* __restrict__ cfeats, const float* __restrict__ opemb)
{
    const int wv = threadIdx.x >> 6, lane = threadIdx.x & 63;
    const int d = blockIdx.x*4 + wv;
    int b = g_off[d], e = g_off[d+1];
    float a_cf=0.f, a_op=0.f, aon=0.f;
    for (int i=b;i<e;i++){
        int s = g_srcarr[i];
        float on = g_onorm[s];
        a_cf += fmaxf(cfeats[(size_t)s*CFF+lane],0.f)*on;
        if (lane < OPEE){
            int ct = clampi(ctypes[s],0,255);
            a_op += fmaxf(opemb[ct*OPEE+lane],0.f)*on;
        }
        aon += on;
    }
    float* row = g_hf + (size_t)d*HFW0;
    row[lane] = a_cf;
    if (lane < OPEE)  row[CFF+lane] = a_op;
    if (lane == 4)    row[68] = aon;
    if (lane >= 5 && lane < 8) row[64+lane] = 0.f;
    if (lane >= 8 && lane < 24) row[72+(lane-8)] = g_eaggR[(size_t)d*CEE+(lane-8)];
}

// ---------------- layer-0 GEMM: no LDS, wave-uniform hf loads; writes xn0 ----------------
__global__ __launch_bounds__(256) void k_gemm0(
    const float* __restrict__ cW0, const float* __restrict__ cb0)
{
    const int d0 = blockIdx.x*NPB;
    const int col = threadIdx.x;
    const float* hfb = g_hf + (size_t)d0*HFW0;
    float acc[NPB];
    #pragma unroll
    for (int n=0;n<NPB;n++) acc[n]=0.f;
    for (int k4=0;k4<16;k4++){                      // cfeats rows
        float w0=cW0[(size_t)(4*k4+0)*NHH+col];
        float w1=cW0[(size_t)(4*k4+1)*NHH+col];
        float w2=cW0[(size_t)(4*k4+2)*NHH+col];
        float w3=cW0[(size_t)(4*k4+3)*NHH+col];
        #pragma unroll
        for (int n=0;n<NPB;n++){
            float4 h4 = *((const float4*)(hfb + (size_t)n*HFW0) + k4);
            acc[n] += h4.x*w0 + h4.y*w1 + h4.z*w2 + h4.w*w3;
        }
    }
    {                                                // opemb rows
        float w0=cW0[(size_t)(CFF+0)*NHH+col];
        float w1=cW0[(size_t)(CFF+1)*NHH+col];
        float w2=cW0[(size_t)(CFF+2)*NHH+col];
        float w3=cW0[(size_t)(CFF+3)*NHH+col];
        #pragma unroll
        for (int n=0;n<NPB;n++){
            float4 h4 = *((const float4*)(hfb + (size_t)n*HFW0) + 16);
            acc[n] += h4.x*w0 + h4.y*w1 + h4.z*w2 + h4.w*w3;
        }
    }
    {                                                // s_on * v0 (collapsed t_flat)
        float w=g_v0[col];
        #pragma unroll
        for (int n=0;n<NPB;n++) acc[n] += hfb[(size_t)n*HFW0+68]*w;
    }
    const float* We = cW0 + (size_t)(CFF+OPEE+TGG*NHH)*NHH;
    for (int f4=0;f4<4;f4++){                        // cedge rows
        float w0=We[(size_t)(4*f4+0)*NHH+col];
        float w1=We[(size_t)(4*f4+1)*NHH+col];
        float w2=We[(size_t)(4*f4+2)*NHH+col];
        float w3=We[(size_t)(4*f4+3)*NHH+col];
        #pragma unroll
        for (int n=0;n<NPB;n++){
            float4 h4 = *((const float4*)(hfb + (size_t)n*HFW0) + 18 + f4);
            acc[n] += h4.x*w0 + h4.y*w1 + h4.z*w2 + h4.w*w3;
        }
    }
    float bb=cb0[col];
    #pragma unroll
    for (int n=0;n<NPB;n++){
        int d=d0+n;
        g_x0[(size_t)d*NHH+col]=fmaxf(acc[n]*g_inorm[d]+bb,0.f)*g_onorm[d];
    }
}

// ---------------- recurrent gather: one wave per node, xn pre-normalized ----------------
template<int DIR>   // DIR=0: read g_x0, DIR=1: read g_x1
__global__ __launch_bounds__(256) void k_gather(){
    const float* xn = DIR ? g_x1 : g_x0;
    const int wv = threadIdx.x >> 6, lane = threadIdx.x & 63;
    const int d = blockIdx.x*4 + wv;
    int b = g_off[d], e = g_off[d+1];
    float4 a = make_float4(0.f,0.f,0.f,0.f);
    int i = b;
    for (; i+1 < e; i += 2){
        int s0 = g_srcarr[i], s1 = g_srcarr[i+1];
        float4 v0 = *((const float4*)(xn + (size_t)s0*NHH) + lane);
        float4 v1 = *((const float4*)(xn + (size_t)s1*NHH) + lane);
        a.x += v0.x; a.y += v0.y; a.z += v0.z; a.w += v0.w;
        a.x += v1.x; a.y += v1.y; a.z += v1.z; a.w += v1.w;
    }
    if (i < e){
        int s0 = g_srcarr[i];
        float4 v0 = *((const float4*)(xn + (size_t)s0*NHH) + lane);
        a.x += v0.x; a.y += v0.y; a.z += v0.z; a.w += v0.w;
    }
    float* row = g_hf + (size_t)d*HFW;
    *((float4*)row + lane) = a;
    if (lane < CEE) row[NHH+lane] = g_eagg[(size_t)d*CEE+lane];
}

// ---------------- recurrent GEMM: no LDS, wave-uniform hf loads ----------------
template<int DIR>   // DIR=0: residual/in g_x0 -> out g_x1; DIR=1: reverse
__global__ __launch_bounds__(256) void k_gemmr(
    const float* __restrict__ W, const float* __restrict__ bias, int relu_res)
{
    const float* xnin = DIR ? g_x1 : g_x0;
    float*       xout = DIR ? g_x0 : g_x1;
    const int d0 = blockIdx.x*NPB;
    const int col = threadIdx.x;
    const float* hfb = g_hf + (size_t)d0*HFW;
    float acc[NPB];
    #pragma unroll
    for (int n=0;n<NPB;n++) acc[n]=0.f;
    for (int k4=0;k4<HFW/4;k4++){
        float w0=W[(size_t)(4*k4+0)*NHH+col];
        float w1=W[(size_t)(4*k4+1)*NHH+col];
        float w2=W[(size_t)(4*k4+2)*NHH+col];
        float w3=W[(size_t)(4*k4+3)*NHH+col];
        #pragma unroll
        for (int n=0;n<NPB;n++){
            float4 h4 = *((const float4*)(hfb + (size_t)n*HFW) + k4);   // wave-uniform -> s_load
            acc[n] += h4.x*w0 + h4.y*w1 + h4.z*w2 + h4.w*w3;
        }
    }
    float bb = bias[col];
    #pragma unroll
    for (int n=0;n<NPB;n++){
        int d = d0+n;
        float val = acc[n]*g_inorm[d]+bb;
        if (relu_res){
            float y = xnin[(size_t)d*NHH+col] + fmaxf(val,0.f);  // residual on normalized feat
            xout[(size_t)d*NHH+col] = y*g_onorm[d];              // pre-normalize for next layer
        } else {
            xout[(size_t)d*NHH+col] = val;                        // final layer: raw
        }
    }
}

// ---------------- pooling (4 deterministic partials) + heads ----------------
__global__ __launch_bounds__(256) void k_cemb(const int* __restrict__ cgroups){
    int g=blockIdx.x>>2, p=blockIdx.x&3, c=threadIdx.x;
    float s=0.f;
    for (int i=p*25;i<p*25+25;i++){
        int idx=clampi(cgroups[g*GSZ+i],0,NCN-1);
        s += g_x1[(size_t)idx*NHH+c];
    }
    g_cembp[(size_t)(p*GCN+g)*NHH+c]=s;
}

__global__ __launch_bounds__(256) void k_heads(
    const float* __restrict__ sW, const float* __restrict__ sb,
    const float* __restrict__ nW, const float* __restrict__ nb, float* __restrict__ out)
{
    __shared__ float red[256];
    __shared__ float z[9];
    int g=blockIdx.x, t=threadIdx.x;
    float e = g_cembp[(size_t)(0*GCN+g)*NHH+t] + g_cembp[(size_t)(1*GCN+g)*NHH+t]
            + g_cembp[(size_t)(2*GCN+g)*NHH+t] + g_cembp[(size_t)(3*GCN+g)*NHH+t];
    for (int j=0;j<9;j++){
        float w = (j==0) ? nW[t] : sW[t*TGG+(j-1)];
        red[t]=e*w; __syncthreads();
        for (int s=128;s>0;s>>=1){ if (t<s) red[t]+=red[t+s]; __syncthreads(); }
        if (t==0) z[j]=red[0];
        __syncthreads();
    }
    if (t==0){
        float z0 = z[0] + nb[0];
        float lsig = fminf(z0,0.f) - log1pf(expf(-fabsf(z0)));
        out[g*9+0]=lsig;
        float zz[8]; float m=-1e30f;
        for (int j=0;j<8;j++){ zz[j]=z[j+1]+sb[j]; m=fmaxf(m,zz[j]); }
        float s=0.f;
        for (int j=0;j<8;j++) s+=expf(zz[j]-m);
        float lse=m+logf(s);
        for (int j=0;j<8;j++) out[g*9+1+j]=zz[j]-lse;
    }
}

extern "C" void kernel_launch(void* const* d_in, const int* in_sizes, int n_in,
                              void* d_out, int out_size, void* d_ws, size_t ws_size,
                              hipStream_t stream) {
    const int expect[24] = {
        NCN*CFF, ECN*CEE, NTT*TFF, ETT*TEE, 256*OPEE,
        (TFF+TEE)*NHH, NHH, 3*(NHH+TEE)*NHH, 3*NHH,
        (CFF+OPEE+TGG*NHH+CEE)*NHH, NHH, 5*(NHH+CEE)*NHH, 5*NHH,
        NHH*TGG, TGG, NHH, 1,
        NCN, ECN, ECN, ETT, ETT, GCN*GSZ, TGG*2
    };
    if (n_in < 24){
        k_badsize<<<(out_size+255)/256,256,0,stream>>>((float*)d_out, out_size, 2.0e6f);
        return;
    }
    for (int i=0;i<24;i++){
        if (in_sizes[i] != expect[i]){
            k_badsize<<<(out_size+255)/256,256,0,stream>>>((float*)d_out, out_size, 1.0e6f+(float)i);
            return;
        }
    }

    const float* cfeats = (const float*)d_in[0];
    const float* cef    = (const float*)d_in[1];
    const float* tfeats = (const float*)d_in[2];
    const float* tef    = (const float*)d_in[3];
    const float* opemb  = (const float*)d_in[4];
    const float* tW0    = (const float*)d_in[5];
    const float* tb0    = (const float*)d_in[6];
    const float* tWr    = (const float*)d_in[7];
    const float* tbr    = (const float*)d_in[8];
    const float* cW0    = (const float*)d_in[9];
    const float* cb0    = (const float*)d_in[10];
    const float* cWr    = (const float*)d_in[11];
    const float* cbr    = (const float*)d_in[12];
    const float* sW     = (const float*)d_in[13];
    const float* sb     = (const float*)d_in[14];
    const float* nW     = (const float*)d_in[15];
    const float* nb     = (const float*)d_in[16];
    const int* ctypes   = (const int*)d_in[17];
    const int* c_src    = (const int*)d_in[18];
    const int* c_dst    = (const int*)d_in[19];
    const int* t_src    = (const int*)d_in[20];
    const int* t_dst    = (const int*)d_in[21];
    const int* cgroups  = (const int*)d_in[22];
    const int* tgroups  = (const int*)d_in[23];

    const int EB = (ECN+255)/256, NB = (NCN+255)/256;

    k_zero3   <<<NB, 256, 0, stream>>>();
    k_degrees <<<EB, 256, 0, stream>>>(c_src, c_dst);
    k_norms   <<<NB, 256, 0, stream>>>();
    k_scan    <<<1, 1024, 0, stream>>>();
    k_scatter <<<EB, 256, 0, stream>>>(c_dst);
    k_sortfill<<<NCN/4, 256, 0, stream>>>(c_src);
    k_eagg    <<<(NCN+15)/16, 256, 0, stream>>>(cef);

    // topo GNN
    kt_l0    <<<NTT, 256, 0, stream>>>(tfeats, tef, tW0, tb0, t_src, t_dst);
    kt_lr<0> <<<NTT, 256, 0, stream>>>(tef, tWr + (size_t)0*(NHH+TEE)*NHH, tbr + 0*NHH, t_src, t_dst, 1);
    kt_lr<1> <<<NTT, 256, 0, stream>>>(tef, tWr + (size_t)1*(NHH+TEE)*NHH, tbr + 1*NHH, t_src, t_dst, 1);
    kt_lr<0> <<<NTT, 256, 0, stream>>>(tef, tWr + (size_t)2*(NHH+TEE)*NHH, tbr + 2*NHH, t_src, t_dst, 0);
    k_v0     <<<TGG, 256, 0, stream>>>(cW0, tgroups);
    k_v0r    <<<1, 256, 0, stream>>>();

    // cGNN layer 0 (gather + GEMM), xn0 -> g_x0
    k_gather0<<<NCN/4, 256, 0, stream>>>(ctypes, cfeats, opemb);
    k_gemm0  <<<NCN/NPB, 256, 0, stream>>>(cW0, cb0);

    // 5 recurrent layers: xn ping-pong x0 -> x1 -> x0 -> x1 -> x0 -> x1 (final raw in g_x1)
    k_gather<0><<<NCN/4, 256, 0, stream>>>();
    k_gemmr <0><<<NCN/NPB, 256, 0, stream>>>(cWr + (size_t)0*(NHH+CEE)*NHH, cbr + 0*NHH, 1);
    k_gather<1><<<NCN/4, 256, 0, stream>>>();
    k_gemmr <1><<<NCN/NPB, 256, 0, stream>>>(cWr + (size_t)1*(NHH+CEE)*NHH, cbr + 1*NHH, 1);
    k_gather<0><<<NCN/4, 256, 0, stream>>>();
    k_gemmr <0><<<NCN/NPB, 256, 0, stream>>>(cWr + (size_t)2*(NHH+CEE)*NHH, cbr + 2*NHH, 1);
    k_gather<1><<<NCN/4, 256, 0, stream>>>();
    k_gemmr <1><<<NCN/NPB, 256, 0, stream>>>(cWr + (size_t)3*(NHH+CEE)*NHH, cbr + 3*NHH, 1);
    k_gather<0><<<NCN/4, 256, 0, stream>>>();
    k_gemmr <0><<<NCN/NPB, 256, 0, stream>>>(cWr + (size_t)4*(NHH+CEE)*NHH, cbr + 4*NHH, 0);

    k_cemb <<<4*GCN, 256, 0, stream>>>(cgroups);
    k_heads<<<GCN, 256, 0, stream>>>(sW, sb, nW, nb, (float*)d_out);
}